// Round 15
// baseline (176.796 us; speedup 1.0000x reference)
//
#include <hip/hip_runtime.h>
#include <stdint.h>

#define POOL 7
#define NROI 2000
#define MPAD 2048
#define KDIM 12544   // 49*256, K index = pp*256 + c  (PERMUTED layout)
#define A_CNT 261888

typedef __bf16 bf16x8 __attribute__((ext_vector_type(8)));
typedef float f32x4 __attribute__((ext_vector_type(4)));

__device__ __forceinline__ unsigned short f2bf(float f) {
  unsigned int u = __builtin_bit_cast(unsigned int, f);
  u += 0x7FFFu + ((u >> 16) & 1u);
  return (unsigned short)(u >> 16);
}
__device__ __forceinline__ float bf2f(unsigned short h) {
  unsigned int u = ((unsigned int)h) << 16;
  return __builtin_bit_cast(float, u);
}

__device__ __forceinline__ void gload16(const void* g, void* l) {
  __builtin_amdgcn_global_load_lds(
      (const __attribute__((address_space(1))) void*)g,
      (__attribute__((address_space(3))) void*)l, 16, 0, 0);
}

// ===== mega prep kernel: proposals | tfeat(all levels) | w3 | twt(w2) =====
// flat grid 9535: [0,1023) proposals, [1023,6463) tfeat, [6463,8511) w3,
// [8511,9535) twt. All branches 256 thr, shared 8KB LDS buffer (aliased).
#define NB_PROP 1023
#define NB_TF   5440
#define NB_W3   2048
#define NB_TWT  1024

__global__ __launch_bounds__(256) void k_prep(
    const float4* __restrict__ anchors, const float4* __restrict__ deltas,
    float4* __restrict__ prop,
    const float* __restrict__ p2, const float* __restrict__ p3,
    const float* __restrict__ p4, const float* __restrict__ p5,
    unsigned short* __restrict__ t2, unsigned short* __restrict__ t3,
    unsigned short* __restrict__ t4, unsigned short* __restrict__ t5,
    const float* __restrict__ wc, const float* __restrict__ wb,
    unsigned short* __restrict__ w3t,
    const float* __restrict__ w2, unsigned short* __restrict__ w2t) {
  __shared__ unsigned short l[16 * 256];
  int bid = blockIdx.x;
  int tid = threadIdx.x;
  if (bid < NB_PROP) {
    // ---- RPN proposals ----
    int i = bid * 256 + tid;  // 1023*256 == A_CNT exactly
    float4 a = anchors[i], d = deltas[i];
    float h = a.z - a.x, w = a.w - a.y;
    float cy = a.x + 0.5f * h + d.x * h;
    float cx = a.y + 0.5f * w + d.y * w;
    h *= expf(d.z);
    w *= expf(d.w);
    float y1 = cy - 0.5f * h, x1 = cx - 0.5f * w;
    float y2 = y1 + h, x2 = x1 + w;
    y1 = fminf(fmaxf(y1, 0.f), 1.f);
    x1 = fminf(fmaxf(x1, 0.f), 1.f);
    y2 = fminf(fmaxf(y2, 0.f), 1.f);
    x2 = fminf(fmaxf(x2, 0.f), 1.f);
    prop[i] = make_float4(x1, y1, x2, y2);
  } else if (bid < NB_PROP + NB_TF) {
    // ---- feature transpose [C][HW] f32 -> [HW][C] bf16 ----
    int b = bid - NB_PROP;
    const float* f;
    unsigned short* o;
    int hw, p0;
    if (b < 4096)      { f = p2; o = t2; hw = 65536; p0 = b * 16; }
    else if (b < 5120) { f = p3; o = t3; hw = 16384; p0 = (b - 4096) * 16; }
    else if (b < 5376) { f = p4; o = t4; hw = 4096;  p0 = (b - 5120) * 16; }
    else               { f = p5; o = t5; hw = 1024;  p0 = (b - 5376) * 16; }
    const float* src = f + (size_t)tid * hw + p0;
#pragma unroll
    for (int i = 0; i < 16; ++i) l[i * 256 + tid] = f2bf(src[i]);
    __syncthreads();
    size_t base = (size_t)p0 * 256;
#pragma unroll 4
    for (int i = tid; i < 16 * 256; i += 256) o[base + i] = l[i];
  } else if (bid < NB_PROP + NB_TF + NB_W3) {
    // ---- combined cls|bbox weight, transposed [512][1024] bf16 ----
    int idx = (bid - NB_PROP - NB_TF) * 256 + tid;
    int n = idx >> 10, k = idx & 1023;
    float v = 0.f;
    if (n < 81) v = wc[k * 81 + n];
    else if (n < 405) v = wb[k * 324 + (n - 81)];
    w3t[idx] = f2bf(v);
  } else {
    // ---- w2 transpose [1024][1024] f32 -> [1024][1024] bf16 ----
    int local = bid - NB_PROP - NB_TF - NB_W3;
    int c0 = (local & 31) * 32, r0 = (local >> 5) * 32;
    int tx = tid & 31, ty = tid >> 5;  // 32 x 8
    unsigned short (*t)[33] = (unsigned short(*)[33])l;
    for (int i = ty; i < 32; i += 8)
      t[i][tx] = f2bf(w2[(size_t)(r0 + i) * 1024 + c0 + tx]);
    __syncthreads();
    for (int i = ty; i < 32; i += 8)
      w2t[(size_t)(c0 + i) * 1024 + r0 + tx] = t[tx][i];
  }
}

// ---- w1 transpose+permute v2: w1[K=c*49+pp][1024] f32 -> w1t[n][pp*256+c] bf16 ----
__global__ __launch_bounds__(256) void k_tw1(const float* __restrict__ w1,
                                             unsigned short* __restrict__ out) {
  __shared__ unsigned short lds[32][1032];
  int c0 = blockIdx.x * 32, pp = blockIdx.y;
  int t = threadIdx.x;
  for (int it = 0; it < 64; ++it) {
    int idx = t + it * 256;
    int row = idx >> 9, col2 = idx & 511;
    float2 v = *reinterpret_cast<const float2*>(
        w1 + (size_t)((c0 + row) * 49 + pp) * 1024 + col2 * 2);
    lds[row][col2 * 2] = f2bf(v.x);
    lds[row][col2 * 2 + 1] = f2bf(v.y);
  }
  __syncthreads();
  int m = t & 15, n0 = t >> 4;
  for (int k = 0; k < 64; ++k) {
    int n = n0 + k * 16;
    ushort2 v;
    v.x = lds[2 * m][n];
    v.y = lds[2 * m + 1][n];
    *reinterpret_cast<ushort2*>(out + (size_t)n * KDIM + pp * 256 + c0 + 2 * m) = v;
  }
}

// ------- ROIAlign v3: ushort4 gathers, independent cells, ushort4 copy -------
__global__ __launch_bounds__(256) void k_roialign(
    const float* __restrict__ rois,
    const unsigned short* __restrict__ t2, const unsigned short* __restrict__ t3,
    const unsigned short* __restrict__ t4, const unsigned short* __restrict__ t5,
    unsigned short* __restrict__ xout) {
  __shared__ unsigned short lx[KDIM];
  int n = blockIdx.x;
  int tid = threadIdx.x;
  size_t obase = (size_t)n * KDIM;
  ushort4* xo4 = reinterpret_cast<ushort4*>(xout + obase);
  if (n >= NROI) {
    ushort4 z = {0, 0, 0, 0};
    for (int i = tid; i < KDIM / 4; i += 256) xo4[i] = z;
    return;
  }
  float rx1 = rois[n * 4 + 0], ry1 = rois[n * 4 + 1];
  float rx2 = rois[n * 4 + 2], ry2 = rois[n * 4 + 3];
  float area = (ry2 - ry1) * (rx2 - rx1);
  float lv = rintf(log2f(sqrtf(area) / 224.0f)) + 4.0f;
  int lvl = (int)fminf(fmaxf(lv, 2.0f), 5.0f);
  int H = 1024 >> lvl;  // W == H
  const unsigned short* tf = (lvl == 2) ? t2 : (lvl == 3) ? t3 : (lvl == 4) ? t4 : t5;
  const float inv1024 = 1.0f / 1024.0f;
  float hm1 = (float)(H - 1);
  float y1n = ry1 * inv1024, y2n = ry2 * inv1024;
  float x1n = rx1 * inv1024, x2n = rx2 * inv1024;
  float dy = (y2n - y1n) * hm1, dx = (x2n - x1n) * hm1;
  float by = y1n * hm1, bx = x1n * hm1;
  const float sixth = 1.0f / 6.0f;

  int w = tid >> 6, l = tid & 63;
  int c4 = l * 4;
#pragma unroll
  for (int j = 0; j < 13; ++j) {
    int cell = w + 4 * j;
    if (cell < 49) {
      int py = (cell * 37450) >> 18;  // == cell/7 for cell<49
      int px = cell - py * 7;
      float ys = by + (float)py * sixth * dy;
      float xs = bx + (float)px * sixth * dx;
      float yf = floorf(ys), xf = floorf(xs);
      float fy = ys - yf, fx = xs - xf;
      int y0 = (int)fminf(fmaxf(yf, 0.f), hm1);
      int y1i = (int)fminf(fmaxf(yf + 1.f, 0.f), hm1);
      int x0 = (int)fminf(fmaxf(xf, 0.f), hm1);
      int x1i = (int)fminf(fmaxf(xf + 1.f, 0.f), hm1);
      ushort4 v00 = *reinterpret_cast<const ushort4*>(tf + (size_t)(y0 * H + x0) * 256 + c4);
      ushort4 v01 = *reinterpret_cast<const ushort4*>(tf + (size_t)(y0 * H + x1i) * 256 + c4);
      ushort4 v10 = *reinterpret_cast<const ushort4*>(tf + (size_t)(y1i * H + x0) * 256 + c4);
      ushort4 v11 = *reinterpret_cast<const ushort4*>(tf + (size_t)(y1i * H + x1i) * 256 + c4);
      float w00 = (1.f - fy) * (1.f - fx), w01 = (1.f - fy) * fx;
      float w10 = fy * (1.f - fx), w11 = fy * fx;
      ushort4 o;
      o.x = f2bf(w00 * bf2f(v00.x) + w01 * bf2f(v01.x) + w10 * bf2f(v10.x) + w11 * bf2f(v11.x));
      o.y = f2bf(w00 * bf2f(v00.y) + w01 * bf2f(v01.y) + w10 * bf2f(v10.y) + w11 * bf2f(v11.y));
      o.z = f2bf(w00 * bf2f(v00.z) + w01 * bf2f(v01.z) + w10 * bf2f(v10.z) + w11 * bf2f(v11.z));
      o.w = f2bf(w00 * bf2f(v00.w) + w01 * bf2f(v01.w) + w10 * bf2f(v10.w) + w11 * bf2f(v11.w));
      *reinterpret_cast<ushort4*>(lx + (py * 7 + px) * 256 + c4) = o;
    }
  }
  __syncthreads();
  const ushort4* lx4 = reinterpret_cast<const ushort4*>(lx);
  for (int i = tid; i < KDIM / 4; i += 256) xo4[i] = lx4[i];
}

// ================= GEMM1: counted-vmcnt pipeline (R9-proven) =================
#define G1_BM 128
#define G1_BN 256
#define G1_BK 64
#define G1_KCH (KDIM / 4)   // 3136
#define G1_NK  (G1_KCH / G1_BK)  // 49

__device__ __forceinline__ void g1_compute(const unsigned short* bA,
                                           const unsigned short* bB,
                                           int wm, int wn, int r, int s,
                                           f32x4 acc[4][4]) {
#pragma unroll
  for (int h = 0; h < 2; ++h) {
    int off = ((h * 4 + s) ^ (r & 7)) * 8;
    bf16x8 af[4], bv[4];
#pragma unroll
    for (int m = 0; m < 4; ++m)
      af[m] = *reinterpret_cast<const bf16x8*>(bA + (wm + m * 16 + r) * 64 + off);
#pragma unroll
    for (int nn = 0; nn < 4; ++nn)
      bv[nn] = *reinterpret_cast<const bf16x8*>(bB + (wn + nn * 16 + r) * 64 + off);
    __builtin_amdgcn_s_setprio(1);
#pragma unroll
    for (int m = 0; m < 4; ++m)
#pragma unroll
      for (int nn = 0; nn < 4; ++nn)
        acc[m][nn] = __builtin_amdgcn_mfma_f32_16x16x32_bf16(af[m], bv[nn], acc[m][nn], 0, 0, 0);
    __builtin_amdgcn_s_setprio(0);
  }
}

__global__ __launch_bounds__(512, 2) void k_gemm1(
    const unsigned short* __restrict__ A,   // [2048][12544] bf16
    const unsigned short* __restrict__ Bt,  // [1024][12544] bf16
    float* __restrict__ part) {             // [4][2048][1024] f32
  constexpr int K = KDIM, N = 1024, M = MPAD;
  __shared__ unsigned short lA[3][G1_BM * G1_BK];  // 3 x 16KB
  __shared__ unsigned short lB[3][G1_BN * G1_BK];  // 3 x 32KB
  int tid = threadIdx.x;

  int orig = blockIdx.x;
  int swz = (orig & 7) * 32 + (orig >> 3);
  int ksp = swz >> 6;
  int tile = swz & 63;
  int bm = (tile >> 2) * G1_BM;
  int bn = (tile & 3) * G1_BN;
  int kbeg = ksp * G1_KCH;

  int lane = tid & 63, wid = tid >> 6;
  int wm = (wid >> 2) * 64, wn = (wid & 3) * 64;
  int r = lane & 15, s = lane >> 4;

  f32x4 acc[4][4] = {};

  int rb = tid >> 3;                                // 0..63
  int srccol = ((tid & 7) ^ ((tid >> 3) & 7)) * 8;  // pre-swizzled source col
  int ea = tid * 8;                                 // linear dest elem offset
  const unsigned short* gA0 = A + (size_t)(bm + rb) * K + kbeg + srccol;
  const unsigned short* gA1 = gA0 + (size_t)64 * K;
  const unsigned short* gB0 = Bt + (size_t)(bn + rb) * K + kbeg + srccol;
  const unsigned short* gB1 = gB0 + (size_t)64 * K;
  const unsigned short* gB2 = gB0 + (size_t)128 * K;
  const unsigned short* gB3 = gB0 + (size_t)192 * K;

#define G1_STAGE(buf, kt)                         \
  do {                                            \
    int k0 = (kt) * G1_BK;                        \
    gload16(gA0 + k0, lA[buf] + ea);              \
    gload16(gA1 + k0, lA[buf] + ea + 4096);       \
    gload16(gB0 + k0, lB[buf] + ea);              \
    gload16(gB1 + k0, lB[buf] + ea + 4096);       \
    gload16(gB2 + k0, lB[buf] + ea + 8192);       \
    gload16(gB3 + k0, lB[buf] + ea + 12288);      \
  } while (0)

#define G1_ITER(buf, nxt, kt)                          \
  do {                                                 \
    asm volatile("s_waitcnt vmcnt(6)" ::: "memory");   \
    __builtin_amdgcn_s_barrier();                      \
    asm volatile("" ::: "memory");                     \
    if ((kt) + 2 < G1_NK) G1_STAGE(nxt, (kt) + 2);     \
    g1_compute(lA[buf], lB[buf], wm, wn, r, s, acc);   \
  } while (0)

  G1_STAGE(0, 0);
  G1_STAGE(1, 1);

  for (int g = 0; g < 16; ++g) {
    int kt = g * 3;
    G1_ITER(0, 2, kt);
    G1_ITER(1, 0, kt + 1);
    G1_ITER(2, 1, kt + 2);
  }
  asm volatile("s_waitcnt vmcnt(0)" ::: "memory");
  __builtin_amdgcn_s_barrier();
  asm volatile("" ::: "memory");
  g1_compute(lA[0], lB[0], wm, wn, r, s, acc);

  float* pout = part + (size_t)ksp * M * N;
#pragma unroll
  for (int m = 0; m < 4; ++m) {
#pragma unroll
    for (int nn = 0; nn < 4; ++nn) {
      int gcol = bn + wn + nn * 16 + r;
#pragma unroll
      for (int rr = 0; rr < 4; ++rr) {
        int grow = bm + wm + m * 16 + s * 4 + rr;
        pout[(size_t)grow * N + gcol] = acc[m][nn][rr];
      }
    }
  }
#undef G1_STAGE
#undef G1_ITER
}

// ==== GEMM2/3: direct-output counted-vmcnt pipeline, K=1024, nk=16, BN templated ====
#define GD_NK 16

template <int EPI, int BNT>
__global__ __launch_bounds__(256, 2) void k_gemm_dir(
    const unsigned short* __restrict__ A,   // [M][1024] bf16
    const unsigned short* __restrict__ Bt,  // [N][1024] bf16
    const float* __restrict__ bias,         // EPI0: [N]; EPI1: b_cls
    const float* __restrict__ bias2,        // EPI1: b_bbox
    unsigned short* __restrict__ outb,      // EPI0
    float* __restrict__ cls, float* __restrict__ bbox,  // EPI1
    int N, int ntn) {
  constexpr int K = 1024;
  constexpr int NBF = BNT / 32;  // B-frags per wave / B-halves per stage
  __shared__ unsigned short lA[3][64 * 64];    // 3 x 8KB
  __shared__ unsigned short lB[3][BNT * 64];   // 3 x (BNT/8)KB
  int tid = threadIdx.x;

  int nwg = gridDim.x;
  int chunk = nwg >> 3;
  int orig = blockIdx.x;
  int tile = (orig & 7) * chunk + (orig >> 3);  // XCD-chunked, bijective
  int bm = (tile / ntn) * 64;
  int bn = (tile % ntn) * BNT;

  int lane = tid & 63, wid = tid >> 6;
  int wm = (wid >> 1) * 32, wn = (wid & 1) * (BNT / 2);
  int r = lane & 15, s = lane >> 4;

  f32x4 acc[2][NBF] = {};

  int rb = tid >> 3;
  int srccol = ((tid & 7) ^ ((tid >> 3) & 7)) * 8;
  int ea = tid * 8;
  const unsigned short* gA0 = A + (size_t)(bm + rb) * K + srccol;
  const unsigned short* gA1 = gA0 + (size_t)32 * K;
  const unsigned short* gB[4];
  gB[0] = Bt + (size_t)(bn + rb) * K + srccol;
#pragma unroll
  for (int q = 1; q < NBF; ++q) gB[q] = gB[0] + (size_t)(32 * q) * K;

#define GD_STAGE(buf, kt)                                    \
  do {                                                       \
    int k0 = (kt) * 64;                                      \
    gload16(gA0 + k0, lA[buf] + ea);                         \
    gload16(gA1 + k0, lA[buf] + ea + 2048);                  \
    _Pragma("unroll")                                        \
    for (int q = 0; q < NBF; ++q)                            \
      gload16(gB[q] + k0, lB[buf] + ea + q * 2048);          \
  } while (0)

#define GD_BODY(buf)                                                            \
  do {                                                                          \
    const unsigned short* bA = lA[buf];                                         \
    const unsigned short* bB = lB[buf];                                         \
    _Pragma("unroll")                                                           \
    for (int h = 0; h < 2; ++h) {                                               \
      int off = ((h * 4 + s) ^ (r & 7)) * 8;                                    \
      bf16x8 af[2], bv[NBF];                                                    \
      _Pragma("unroll")                                                         \
      for (int m = 0; m < 2; ++m)                                               \
        af[m] = *reinterpret_cast<const bf16x8*>(bA + (wm + m * 16 + r) * 64 + off); \
      _Pragma("unroll")                                                         \
      for (int nn = 0; nn < NBF; ++nn)                                          \
        bv[nn] = *reinterpret_cast<const bf16x8*>(bB + (wn + nn * 16 + r) * 64 + off); \
      __builtin_amdgcn_s_setprio(1);                                            \
      _Pragma("unroll")                                                         \
      for (int m = 0; m < 2; ++m)                                               \
        _Pragma("unroll")                                                       \
        for (int nn = 0; nn < NBF; ++nn)                                        \
          acc[m][nn] = __builtin_amdgcn_mfma_f32_16x16x32_bf16(af[m], bv[nn], acc[m][nn], 0, 0, 0); \
      __builtin_amdgcn_s_setprio(0);                                            \
    }                                                                           \
  } while (0)

#define GD_ITER(buf, nxt, kt)                                 \
  do {                                                        \
    if constexpr (BNT == 128)                                 \
      asm volatile("s_waitcnt vmcnt(6)" ::: "memory");        \
    else                                                      \
      asm volatile("s_waitcnt vmcnt(4)" ::: "memory");        \
    __builtin_amdgcn_s_barrier();                             \
    asm volatile("" ::: "memory");                            \
    if ((kt) + 2 < GD_NK) GD_STAGE(nxt, (kt) + 2);            \
    GD_BODY(buf);                                             \
  } while (0)

  GD_STAGE(0, 0);
  GD_STAGE(1, 1);
  for (int g = 0; g < 5; ++g) {
    int kt = g * 3;
    GD_ITER(0, 2, kt);
    GD_ITER(1, 0, kt + 1);
    GD_ITER(2, 1, kt + 2);
  }
  asm volatile("s_waitcnt vmcnt(0)" ::: "memory");
  __builtin_amdgcn_s_barrier();
  asm volatile("" ::: "memory");
  GD_BODY(0);

#pragma unroll
  for (int m = 0; m < 2; ++m) {
#pragma unroll
    for (int nn = 0; nn < NBF; ++nn) {
      int gcol = bn + wn + nn * 16 + r;
#pragma unroll
      for (int rr = 0; rr < 4; ++rr) {
        int grow = bm + wm + m * 16 + s * 4 + rr;
        float v = acc[m][nn][rr];
        if constexpr (EPI == 0) {
          v = fmaxf(v + bias[gcol], 0.f);
          outb[(size_t)grow * 1024 + gcol] = f2bf(v);
        } else {
          if (grow < NROI) {
            if (gcol < 81) cls[(size_t)grow * 81 + gcol] = v + bias[gcol];
            else if (gcol < 405) bbox[(size_t)grow * 324 + (gcol - 81)] = v + bias2[gcol - 81];
          }
        }
      }
    }
  }
#undef GD_STAGE
#undef GD_BODY
#undef GD_ITER
}

// ---------------- split-K reduce + bias + relu -> bf16 (4 partials, GEMM1) ----------------
__global__ __launch_bounds__(256) void k_reduce_relu(
    const float4* __restrict__ part, const float* __restrict__ bias,
    ushort4* __restrict__ out, int MNv, int Nv) {
  int i = blockIdx.x * 256 + threadIdx.x;
  if (i >= MNv) return;
  float4 s = part[i];
#pragma unroll
  for (int k = 1; k < 4; ++k) {
    float4 t = part[(size_t)k * MNv + i];
    s.x += t.x; s.y += t.y; s.z += t.z; s.w += t.w;
  }
  int c4 = (i & (Nv - 1)) * 4;
  s.x = fmaxf(s.x + bias[c4 + 0], 0.f);
  s.y = fmaxf(s.y + bias[c4 + 1], 0.f);
  s.z = fmaxf(s.z + bias[c4 + 2], 0.f);
  s.w = fmaxf(s.w + bias[c4 + 3], 0.f);
  ushort4 o;
  o.x = f2bf(s.x); o.y = f2bf(s.y); o.z = f2bf(s.z); o.w = f2bf(s.w);
  out[i] = o;
}

extern "C" void kernel_launch(void* const* d_in, const int* in_sizes, int n_in,
                              void* d_out, int out_size, void* d_ws, size_t ws_size,
                              hipStream_t stream) {
  (void)in_sizes; (void)n_in; (void)out_size; (void)ws_size;
  const float* p2 = (const float*)d_in[0];
  const float* p3 = (const float*)d_in[1];
  const float* p4 = (const float*)d_in[2];
  const float* p5 = (const float*)d_in[3];
  const float* rois = (const float*)d_in[4];
  const float* anchors = (const float*)d_in[5];
  const float* rpn = (const float*)d_in[6];
  const float* w1 = (const float*)d_in[7];
  const float* b1 = (const float*)d_in[8];
  const float* w2 = (const float*)d_in[9];
  const float* b2 = (const float*)d_in[10];
  const float* wc = (const float*)d_in[11];
  const float* bc = (const float*)d_in[12];
  const float* wb = (const float*)d_in[13];
  const float* bb = (const float*)d_in[14];

  float* out_prop = (float*)d_out;
  float* out_cls = out_prop + (size_t)A_CNT * 4;
  float* out_bbox = out_cls + (size_t)NROI * 81;

  char* ws = (char*)d_ws;
  size_t off = 0;
  auto alloc = [&](size_t bytes) {
    void* p = ws + off;
    off += (bytes + 255) & ~(size_t)255;
    return p;
  };
  unsigned short* xb  = (unsigned short*)alloc((size_t)MPAD * KDIM * 2);   // 51.4MB
  unsigned short* w1t = (unsigned short*)alloc((size_t)1024 * KDIM * 2);   // 25.7MB
  unsigned short* w2t = (unsigned short*)alloc((size_t)1024 * 1024 * 2);   // 2.1MB
  unsigned short* w3t = (unsigned short*)alloc((size_t)512 * 1024 * 2);    // 1.0MB
  // contiguous scratch: feature maps live here until roialign is done, then
  // reused for GEMM1 split-K partials (32MB) + h1 (4MB) + h2 (4MB).
  char* scratch = (char*)alloc((size_t)(65536 + 16384 + 4096 + 1024) * 256 * 2);  // 44.6MB
  unsigned short* t2 = (unsigned short*)scratch;
  unsigned short* t3 = t2 + (size_t)65536 * 256;
  unsigned short* t4 = t3 + (size_t)16384 * 256;
  unsigned short* t5 = t4 + (size_t)4096 * 256;
  float* part = (float*)scratch;  // 4x2048x1024 f32 = 32MB
  unsigned short* h1 = (unsigned short*)(scratch + (size_t)4 * MPAD * 1024 * 4);
  unsigned short* h2 = h1 + (size_t)MPAD * 1024;

  // fused prep: proposals | tfeat(all) | w3 | twt(w2)
  k_prep<<<NB_PROP + NB_TF + NB_W3 + NB_TWT, 256, 0, stream>>>(
      (const float4*)anchors, (const float4*)rpn, (float4*)d_out,
      p2, p3, p4, p5, t2, t3, t4, t5, wc, wb, w3t, w2, w2t);
  k_tw1<<<dim3(8, 49), 256, 0, stream>>>(w1, w1t);
  k_roialign<<<MPAD, 256, 0, stream>>>(rois, t2, t3, t4, t5, xb);

  // GEMM1: counted-vmcnt pipeline, 64 tiles (16x4) x ksplit 4 -> 256 blocks
  k_gemm1<<<256, 512, 0, stream>>>(xb, w1t, part);
  k_reduce_relu<<<MPAD * 1024 / 4 / 256, 256, 0, stream>>>(
      (const float4*)part, b1, (ushort4*)h1, MPAD * 1024 / 4, 1024 / 4);

  // GEMM2: [2048,1024]@[1024,1024] direct, 32x8=256 blocks, fused bias+relu
  k_gemm_dir<0, 128><<<256, 256, 0, stream>>>(h1, w2t, b2, nullptr, h2, nullptr, nullptr,
                                              1024, 8);

  // GEMM3: [2048,1024]@[1024,512] direct, BN=64 -> 32x8=256 blocks, fused scatter
  k_gemm_dir<1, 64><<<256, 256, 0, stream>>>(h2, w3t, bc, bb, nullptr, out_cls, out_bbox,
                                             512, 8);
}

// Round 16
// 173.554 us; speedup vs baseline: 1.0187x; 1.0187x over previous
//
#include <hip/hip_runtime.h>
#include <stdint.h>

#define POOL 7
#define NROI 2000
#define MPAD 2048
#define KDIM 12544   // 49*256, K index = pp*256 + c  (PERMUTED layout)
#define A_CNT 261888

typedef __bf16 bf16x8 __attribute__((ext_vector_type(8)));
typedef float f32x4 __attribute__((ext_vector_type(4)));
typedef _Float16 f16x8 __attribute__((ext_vector_type(8)));

__device__ __forceinline__ unsigned short f2bf(float f) {
  unsigned int u = __builtin_bit_cast(unsigned int, f);
  u += 0x7FFFu + ((u >> 16) & 1u);
  return (unsigned short)(u >> 16);
}
__device__ __forceinline__ float bf2f(unsigned short h) {
  unsigned int u = ((unsigned int)h) << 16;
  return __builtin_bit_cast(float, u);
}

__device__ __forceinline__ void gload16(const void* g, void* l) {
  __builtin_amdgcn_global_load_lds(
      (const __attribute__((address_space(1))) void*)g,
      (__attribute__((address_space(3))) void*)l, 16, 0, 0);
}

// ===== mega prep kernel: proposals | tfeat(all levels) | w3 | twt(w2) =====
#define NB_PROP 1023
#define NB_TF   5440
#define NB_W3   2048
#define NB_TWT  1024

__global__ __launch_bounds__(256) void k_prep(
    const float4* __restrict__ anchors, const float4* __restrict__ deltas,
    float4* __restrict__ prop,
    const float* __restrict__ p2, const float* __restrict__ p3,
    const float* __restrict__ p4, const float* __restrict__ p5,
    unsigned short* __restrict__ t2, unsigned short* __restrict__ t3,
    unsigned short* __restrict__ t4, unsigned short* __restrict__ t5,
    const float* __restrict__ wc, const float* __restrict__ wb,
    unsigned short* __restrict__ w3t,
    const float* __restrict__ w2, unsigned short* __restrict__ w2t) {
  __shared__ unsigned short l[16 * 256];
  int bid = blockIdx.x;
  int tid = threadIdx.x;
  if (bid < NB_PROP) {
    int i = bid * 256 + tid;  // 1023*256 == A_CNT exactly
    float4 a = anchors[i], d = deltas[i];
    float h = a.z - a.x, w = a.w - a.y;
    float cy = a.x + 0.5f * h + d.x * h;
    float cx = a.y + 0.5f * w + d.y * w;
    h *= expf(d.z);
    w *= expf(d.w);
    float y1 = cy - 0.5f * h, x1 = cx - 0.5f * w;
    float y2 = y1 + h, x2 = x1 + w;
    y1 = fminf(fmaxf(y1, 0.f), 1.f);
    x1 = fminf(fmaxf(x1, 0.f), 1.f);
    y2 = fminf(fmaxf(y2, 0.f), 1.f);
    x2 = fminf(fmaxf(x2, 0.f), 1.f);
    prop[i] = make_float4(x1, y1, x2, y2);
  } else if (bid < NB_PROP + NB_TF) {
    int b = bid - NB_PROP;
    const float* f;
    unsigned short* o;
    int hw, p0;
    if (b < 4096)      { f = p2; o = t2; hw = 65536; p0 = b * 16; }
    else if (b < 5120) { f = p3; o = t3; hw = 16384; p0 = (b - 4096) * 16; }
    else if (b < 5376) { f = p4; o = t4; hw = 4096;  p0 = (b - 5120) * 16; }
    else               { f = p5; o = t5; hw = 1024;  p0 = (b - 5376) * 16; }
    const float* src = f + (size_t)tid * hw + p0;
#pragma unroll
    for (int i = 0; i < 16; ++i) l[i * 256 + tid] = f2bf(src[i]);
    __syncthreads();
    size_t base = (size_t)p0 * 256;
#pragma unroll 4
    for (int i = tid; i < 16 * 256; i += 256) o[base + i] = l[i];
  } else if (bid < NB_PROP + NB_TF + NB_W3) {
    int idx = (bid - NB_PROP - NB_TF) * 256 + tid;
    int n = idx >> 10, k = idx & 1023;
    float v = 0.f;
    if (n < 81) v = wc[k * 81 + n];
    else if (n < 405) v = wb[k * 324 + (n - 81)];
    w3t[idx] = f2bf(v);
  } else {
    int local = bid - NB_PROP - NB_TF - NB_W3;
    int c0 = (local & 31) * 32, r0 = (local >> 5) * 32;
    int tx = tid & 31, ty = tid >> 5;  // 32 x 8
    unsigned short (*t)[33] = (unsigned short(*)[33])l;
    for (int i = ty; i < 32; i += 8)
      t[i][tx] = f2bf(w2[(size_t)(r0 + i) * 1024 + c0 + tx]);
    __syncthreads();
    for (int i = ty; i < 32; i += 8)
      w2t[(size_t)(c0 + i) * 1024 + r0 + tx] = t[tx][i];
  }
}

// ---- w1 transpose+permute v2: w1[K=c*49+pp][1024] f32 -> w1t[n][pp*256+c] bf16 ----
__global__ __launch_bounds__(256) void k_tw1(const float* __restrict__ w1,
                                             unsigned short* __restrict__ out) {
  __shared__ unsigned short lds[32][1032];
  int c0 = blockIdx.x * 32, pp = blockIdx.y;
  int t = threadIdx.x;
  for (int it = 0; it < 64; ++it) {
    int idx = t + it * 256;
    int row = idx >> 9, col2 = idx & 511;
    float2 v = *reinterpret_cast<const float2*>(
        w1 + (size_t)((c0 + row) * 49 + pp) * 1024 + col2 * 2);
    lds[row][col2 * 2] = f2bf(v.x);
    lds[row][col2 * 2 + 1] = f2bf(v.y);
  }
  __syncthreads();
  int m = t & 15, n0 = t >> 4;
  for (int k = 0; k < 64; ++k) {
    int n = n0 + k * 16;
    ushort2 v;
    v.x = lds[2 * m][n];
    v.y = lds[2 * m + 1][n];
    *reinterpret_cast<ushort2*>(out + (size_t)n * KDIM + pp * 256 + c0 + 2 * m) = v;
  }
}

// ------- ROIAlign v3: ushort4 gathers, independent cells, ushort4 copy -------
__global__ __launch_bounds__(256) void k_roialign(
    const float* __restrict__ rois,
    const unsigned short* __restrict__ t2, const unsigned short* __restrict__ t3,
    const unsigned short* __restrict__ t4, const unsigned short* __restrict__ t5,
    unsigned short* __restrict__ xout) {
  __shared__ unsigned short lx[KDIM];
  int n = blockIdx.x;
  int tid = threadIdx.x;
  size_t obase = (size_t)n * KDIM;
  ushort4* xo4 = reinterpret_cast<ushort4*>(xout + obase);
  if (n >= NROI) {
    ushort4 z = {0, 0, 0, 0};
    for (int i = tid; i < KDIM / 4; i += 256) xo4[i] = z;
    return;
  }
  float rx1 = rois[n * 4 + 0], ry1 = rois[n * 4 + 1];
  float rx2 = rois[n * 4 + 2], ry2 = rois[n * 4 + 3];
  float area = (ry2 - ry1) * (rx2 - rx1);
  float lv = rintf(log2f(sqrtf(area) / 224.0f)) + 4.0f;
  int lvl = (int)fminf(fmaxf(lv, 2.0f), 5.0f);
  int H = 1024 >> lvl;  // W == H
  const unsigned short* tf = (lvl == 2) ? t2 : (lvl == 3) ? t3 : (lvl == 4) ? t4 : t5;
  const float inv1024 = 1.0f / 1024.0f;
  float hm1 = (float)(H - 1);
  float y1n = ry1 * inv1024, y2n = ry2 * inv1024;
  float x1n = rx1 * inv1024, x2n = rx2 * inv1024;
  float dy = (y2n - y1n) * hm1, dx = (x2n - x1n) * hm1;
  float by = y1n * hm1, bx = x1n * hm1;
  const float sixth = 1.0f / 6.0f;

  int w = tid >> 6, l = tid & 63;
  int c4 = l * 4;
#pragma unroll
  for (int j = 0; j < 13; ++j) {
    int cell = w + 4 * j;
    if (cell < 49) {
      int py = (cell * 37450) >> 18;  // == cell/7 for cell<49
      int px = cell - py * 7;
      float ys = by + (float)py * sixth * dy;
      float xs = bx + (float)px * sixth * dx;
      float yf = floorf(ys), xf = floorf(xs);
      float fy = ys - yf, fx = xs - xf;
      int y0 = (int)fminf(fmaxf(yf, 0.f), hm1);
      int y1i = (int)fminf(fmaxf(yf + 1.f, 0.f), hm1);
      int x0 = (int)fminf(fmaxf(xf, 0.f), hm1);
      int x1i = (int)fminf(fmaxf(xf + 1.f, 0.f), hm1);
      ushort4 v00 = *reinterpret_cast<const ushort4*>(tf + (size_t)(y0 * H + x0) * 256 + c4);
      ushort4 v01 = *reinterpret_cast<const ushort4*>(tf + (size_t)(y0 * H + x1i) * 256 + c4);
      ushort4 v10 = *reinterpret_cast<const ushort4*>(tf + (size_t)(y1i * H + x0) * 256 + c4);
      ushort4 v11 = *reinterpret_cast<const ushort4*>(tf + (size_t)(y1i * H + x1i) * 256 + c4);
      float w00 = (1.f - fy) * (1.f - fx), w01 = (1.f - fy) * fx;
      float w10 = fy * (1.f - fx), w11 = fy * fx;
      ushort4 o;
      o.x = f2bf(w00 * bf2f(v00.x) + w01 * bf2f(v01.x) + w10 * bf2f(v10.x) + w11 * bf2f(v11.x));
      o.y = f2bf(w00 * bf2f(v00.y) + w01 * bf2f(v01.y) + w10 * bf2f(v10.y) + w11 * bf2f(v11.y));
      o.z = f2bf(w00 * bf2f(v00.z) + w01 * bf2f(v01.z) + w10 * bf2f(v10.z) + w11 * bf2f(v11.z));
      o.w = f2bf(w00 * bf2f(v00.w) + w01 * bf2f(v01.w) + w10 * bf2f(v10.w) + w11 * bf2f(v11.w));
      *reinterpret_cast<ushort4*>(lx + (py * 7 + px) * 256 + c4) = o;
    }
  }
  __syncthreads();
  const ushort4* lx4 = reinterpret_cast<const ushort4*>(lx);
  for (int i = tid; i < KDIM / 4; i += 256) xo4[i] = lx4[i];
}

// ===== GEMM1: R9 sync skeleton, bigger-wave geometry (LDS-traffic fix) =====
// 256x256 tile, BK=32, 8 waves of 128x64 (wave perimeter 192 @ 2x area ->
// per-K-tile LDS read 96KB vs 128KB). LDS 3x32KB=96KB -> 8 waves/CU (2/SIMD).
// ksplit=8 (kchunk 1568 = 49 K-tiles) -> 256 blocks; partials f16 (32MB).
// Same counted-vmcnt/1-barrier/3-buf/setprio/T2-swizzle structure as R9.
#define G1_KCH (KDIM / 8)        // 1568
#define G1_NK  (G1_KCH / 32)     // 49

__device__ __forceinline__ void g1_compute(const unsigned short* bA,
                                           const unsigned short* bB,
                                           int wm, int wn, int r, int s,
                                           f32x4 acc[8][4]) {
  bf16x8 af[8], bv[4];
#pragma unroll
  for (int m = 0; m < 8; ++m) {
    int row = wm + m * 16 + r;
    af[m] = *reinterpret_cast<const bf16x8*>(bA + row * 32 + ((s ^ ((row >> 1) & 3)) * 8));
  }
#pragma unroll
  for (int nn = 0; nn < 4; ++nn) {
    int row = wn + nn * 16 + r;
    bv[nn] = *reinterpret_cast<const bf16x8*>(bB + row * 32 + ((s ^ ((row >> 1) & 3)) * 8));
  }
  __builtin_amdgcn_s_setprio(1);
#pragma unroll
  for (int m = 0; m < 8; ++m)
#pragma unroll
    for (int nn = 0; nn < 4; ++nn)
      acc[m][nn] = __builtin_amdgcn_mfma_f32_16x16x32_bf16(af[m], bv[nn], acc[m][nn], 0, 0, 0);
  __builtin_amdgcn_s_setprio(0);
}

__global__ __launch_bounds__(512, 2) void k_gemm1(
    const unsigned short* __restrict__ A,   // [2048][12544] bf16
    const unsigned short* __restrict__ Bt,  // [1024][12544] bf16
    unsigned short* __restrict__ part) {    // [8][2048][1024] f16
  constexpr int K = KDIM, N = 1024, M = MPAD;
  __shared__ unsigned short lA[3][256 * 32];  // 3 x 16KB
  __shared__ unsigned short lB[3][256 * 32];  // 3 x 16KB
  int tid = threadIdx.x;

  // XCD-chunked bijective swizzle: 256 blocks, 32/XCD = one ksp per XCD;
  // within chunk, n-tiles inner (consecutive blocks share the A panel).
  int orig = blockIdx.x;
  int swz = (orig & 7) * 32 + (orig >> 3);
  int ksp = swz >> 5;
  int tile = swz & 31;
  int bm = (tile >> 2) * 256;
  int bn = (tile & 3) * 256;
  int kbeg = ksp * G1_KCH;

  int lane = tid & 63, wid = tid >> 6;
  int wm = (wid >> 2) * 128, wn = (wid & 3) * 64;
  int r = lane & 15, s = lane >> 4;

  f32x4 acc[8][4] = {};

  // staging: 64B rows (32 elems); chunk c = tid (+512) -> row c>>2, slot c&3.
  // rows 128+ra have same (row>>1)&3 (128/2 = 64 ≡ 0 mod 4) -> same srccol.
  int ra = tid >> 2;                               // 0..127
  int srccol = ((tid & 3) ^ ((tid >> 3) & 3)) * 8; // pre-swizzled source col
  int ea = tid * 8;                                // linear dest elem offset
  const unsigned short* gA0 = A + (size_t)(bm + ra) * K + kbeg + srccol;
  const unsigned short* gA1 = gA0 + (size_t)128 * K;
  const unsigned short* gB0 = Bt + (size_t)(bn + ra) * K + kbeg + srccol;
  const unsigned short* gB1 = gB0 + (size_t)128 * K;

#define G1_STAGE(buf, kt)                         \
  do {                                            \
    int k0 = (kt) * 32;                           \
    gload16(gA0 + k0, lA[buf] + ea);              \
    gload16(gA1 + k0, lA[buf] + ea + 4096);       \
    gload16(gB0 + k0, lB[buf] + ea);              \
    gload16(gB1 + k0, lB[buf] + ea + 4096);       \
  } while (0)

#define G1_ITER(buf, nxt, kt)                          \
  do {                                                 \
    asm volatile("s_waitcnt vmcnt(4)" ::: "memory");   \
    __builtin_amdgcn_s_barrier();                      \
    asm volatile("" ::: "memory");                     \
    if ((kt) + 2 < G1_NK) G1_STAGE(nxt, (kt) + 2);     \
    g1_compute(lA[buf], lB[buf], wm, wn, r, s, acc);   \
  } while (0)

  G1_STAGE(0, 0);
  G1_STAGE(1, 1);

  for (int g = 0; g < 16; ++g) {
    int kt = g * 3;
    G1_ITER(0, 2, kt);
    G1_ITER(1, 0, kt + 1);
    G1_ITER(2, 1, kt + 2);
  }
  asm volatile("s_waitcnt vmcnt(0)" ::: "memory");
  __builtin_amdgcn_s_barrier();
  asm volatile("" ::: "memory");
  g1_compute(lA[0], lB[0], wm, wn, r, s, acc);

  unsigned short* pout = part + (size_t)ksp * M * N;
#pragma unroll
  for (int m = 0; m < 8; ++m) {
#pragma unroll
    for (int nn = 0; nn < 4; ++nn) {
      int gcol = bn + wn + nn * 16 + r;
#pragma unroll
      for (int rr = 0; rr < 4; ++rr) {
        int grow = bm + wm + m * 16 + s * 4 + rr;
        _Float16 hv = (_Float16)acc[m][nn][rr];
        pout[(size_t)grow * N + gcol] = __builtin_bit_cast(unsigned short, hv);
      }
    }
  }
#undef G1_STAGE
#undef G1_ITER
}

// ---- split-K reduce (8 f16 partials, fixed order) + bias + relu -> bf16 ----
__global__ __launch_bounds__(256) void k_reduce_relu(
    const unsigned short* __restrict__ part, const float* __restrict__ bias,
    unsigned short* __restrict__ out) {
  int i = blockIdx.x * 256 + threadIdx.x;  // over M*N/8 = 262144
  const size_t MN = (size_t)MPAD * 1024;
  size_t base = (size_t)i * 8;
  float sacc[8] = {};
#pragma unroll
  for (int k = 0; k < 8; ++k) {
    f16x8 v = *reinterpret_cast<const f16x8*>(part + k * MN + base);
#pragma unroll
    for (int j = 0; j < 8; ++j) sacc[j] += (float)v[j];
  }
  int c0 = (int)(base & 1023);
  unsigned short o[8];
#pragma unroll
  for (int j = 0; j < 8; ++j)
    o[j] = f2bf(fmaxf(sacc[j] + bias[c0 + j], 0.f));
  *reinterpret_cast<float4*>(out + base) = *reinterpret_cast<const float4*>(o);
}

// ==== GEMM2/3: direct-output counted-vmcnt pipeline, K=1024, nk=16, BN templated ====
#define GD_NK 16

template <int EPI, int BNT>
__global__ __launch_bounds__(256, 2) void k_gemm_dir(
    const unsigned short* __restrict__ A,   // [M][1024] bf16
    const unsigned short* __restrict__ Bt,  // [N][1024] bf16
    const float* __restrict__ bias,         // EPI0: [N]; EPI1: b_cls
    const float* __restrict__ bias2,        // EPI1: b_bbox
    unsigned short* __restrict__ outb,      // EPI0
    float* __restrict__ cls, float* __restrict__ bbox,  // EPI1
    int N, int ntn) {
  constexpr int K = 1024;
  constexpr int NBF = BNT / 32;  // B-frags per wave / B-halves per stage
  __shared__ unsigned short lA[3][64 * 64];    // 3 x 8KB
  __shared__ unsigned short lB[3][BNT * 64];   // 3 x (BNT/8)KB
  int tid = threadIdx.x;

  int nwg = gridDim.x;
  int chunk = nwg >> 3;
  int orig = blockIdx.x;
  int tile = (orig & 7) * chunk + (orig >> 3);  // XCD-chunked, bijective
  int bm = (tile / ntn) * 64;
  int bn = (tile % ntn) * BNT;

  int lane = tid & 63, wid = tid >> 6;
  int wm = (wid >> 1) * 32, wn = (wid & 1) * (BNT / 2);
  int r = lane & 15, s = lane >> 4;

  f32x4 acc[2][NBF] = {};

  int rb = tid >> 3;
  int srccol = ((tid & 7) ^ ((tid >> 3) & 7)) * 8;
  int ea = tid * 8;
  const unsigned short* gA0 = A + (size_t)(bm + rb) * K + srccol;
  const unsigned short* gA1 = gA0 + (size_t)32 * K;
  const unsigned short* gB[4];
  gB[0] = Bt + (size_t)(bn + rb) * K + srccol;
#pragma unroll
  for (int q = 1; q < NBF; ++q) gB[q] = gB[0] + (size_t)(32 * q) * K;

#define GD_STAGE(buf, kt)                                    \
  do {                                                       \
    int k0 = (kt) * 64;                                      \
    gload16(gA0 + k0, lA[buf] + ea);                         \
    gload16(gA1 + k0, lA[buf] + ea + 2048);                  \
    _Pragma("unroll")                                        \
    for (int q = 0; q < NBF; ++q)                            \
      gload16(gB[q] + k0, lB[buf] + ea + q * 2048);          \
  } while (0)

#define GD_BODY(buf)                                                            \
  do {                                                                          \
    const unsigned short* bA = lA[buf];                                         \
    const unsigned short* bB = lB[buf];                                         \
    _Pragma("unroll")                                                           \
    for (int h = 0; h < 2; ++h) {                                               \
      int off = ((h * 4 + s) ^ (r & 7)) * 8;                                    \
      bf16x8 af[2], bv[NBF];                                                    \
      _Pragma("unroll")                                                         \
      for (int m = 0; m < 2; ++m)                                               \
        af[m] = *reinterpret_cast<const bf16x8*>(bA + (wm + m * 16 + r) * 64 + off); \
      _Pragma("unroll")                                                         \
      for (int nn = 0; nn < NBF; ++nn)                                          \
        bv[nn] = *reinterpret_cast<const bf16x8*>(bB + (wn + nn * 16 + r) * 64 + off); \
      __builtin_amdgcn_s_setprio(1);                                            \
      _Pragma("unroll")                                                         \
      for (int m = 0; m < 2; ++m)                                               \
        _Pragma("unroll")                                                       \
        for (int nn = 0; nn < NBF; ++nn)                                        \
          acc[m][nn] = __builtin_amdgcn_mfma_f32_16x16x32_bf16(af[m], bv[nn], acc[m][nn], 0, 0, 0); \
      __builtin_amdgcn_s_setprio(0);                                            \
    }                                                                           \
  } while (0)

#define GD_ITER(buf, nxt, kt)                                 \
  do {                                                        \
    if constexpr (BNT == 128)                                 \
      asm volatile("s_waitcnt vmcnt(6)" ::: "memory");        \
    else                                                      \
      asm volatile("s_waitcnt vmcnt(4)" ::: "memory");        \
    __builtin_amdgcn_s_barrier();                             \
    asm volatile("" ::: "memory");                            \
    if ((kt) + 2 < GD_NK) GD_STAGE(nxt, (kt) + 2);            \
    GD_BODY(buf);                                             \
  } while (0)

  GD_STAGE(0, 0);
  GD_STAGE(1, 1);
  for (int g = 0; g < 5; ++g) {
    int kt = g * 3;
    GD_ITER(0, 2, kt);
    GD_ITER(1, 0, kt + 1);
    GD_ITER(2, 1, kt + 2);
  }
  asm volatile("s_waitcnt vmcnt(0)" ::: "memory");
  __builtin_amdgcn_s_barrier();
  asm volatile("" ::: "memory");
  GD_BODY(0);

#pragma unroll
  for (int m = 0; m < 2; ++m) {
#pragma unroll
    for (int nn = 0; nn < NBF; ++nn) {
      int gcol = bn + wn + nn * 16 + r;
#pragma unroll
      for (int rr = 0; rr < 4; ++rr) {
        int grow = bm + wm + m * 16 + s * 4 + rr;
        float v = acc[m][nn][rr];
        if constexpr (EPI == 0) {
          v = fmaxf(v + bias[gcol], 0.f);
          outb[(size_t)grow * 1024 + gcol] = f2bf(v);
        } else {
          if (grow < NROI) {
            if (gcol < 81) cls[(size_t)grow * 81 + gcol] = v + bias[gcol];
            else if (gcol < 405) bbox[(size_t)grow * 324 + (gcol - 81)] = v + bias2[gcol - 81];
          }
        }
      }
    }
  }
#undef GD_STAGE
#undef GD_BODY
#undef GD_ITER
}

extern "C" void kernel_launch(void* const* d_in, const int* in_sizes, int n_in,
                              void* d_out, int out_size, void* d_ws, size_t ws_size,
                              hipStream_t stream) {
  (void)in_sizes; (void)n_in; (void)out_size; (void)ws_size;
  const float* p2 = (const float*)d_in[0];
  const float* p3 = (const float*)d_in[1];
  const float* p4 = (const float*)d_in[2];
  const float* p5 = (const float*)d_in[3];
  const float* rois = (const float*)d_in[4];
  const float* anchors = (const float*)d_in[5];
  const float* rpn = (const float*)d_in[6];
  const float* w1 = (const float*)d_in[7];
  const float* b1 = (const float*)d_in[8];
  const float* w2 = (const float*)d_in[9];
  const float* b2 = (const float*)d_in[10];
  const float* wc = (const float*)d_in[11];
  const float* bc = (const float*)d_in[12];
  const float* wb = (const float*)d_in[13];
  const float* bb = (const float*)d_in[14];

  float* out_prop = (float*)d_out;
  float* out_cls = out_prop + (size_t)A_CNT * 4;
  float* out_bbox = out_cls + (size_t)NROI * 81;

  char* ws = (char*)d_ws;
  size_t off = 0;
  auto alloc = [&](size_t bytes) {
    void* p = ws + off;
    off += (bytes + 255) & ~(size_t)255;
    return p;
  };
  unsigned short* xb  = (unsigned short*)alloc((size_t)MPAD * KDIM * 2);   // 51.4MB
  unsigned short* w1t = (unsigned short*)alloc((size_t)1024 * KDIM * 2);   // 25.7MB
  unsigned short* w2t = (unsigned short*)alloc((size_t)1024 * 1024 * 2);   // 2.1MB
  unsigned short* w3t = (unsigned short*)alloc((size_t)512 * 1024 * 2);    // 1.0MB
  // contiguous scratch: feature maps live here until roialign is done, then
  // reused for GEMM1 f16 split-K partials (32MB) + h1 (4MB) + h2 (4MB).
  char* scratch = (char*)alloc((size_t)(65536 + 16384 + 4096 + 1024) * 256 * 2);  // 44.6MB
  unsigned short* t2 = (unsigned short*)scratch;
  unsigned short* t3 = t2 + (size_t)65536 * 256;
  unsigned short* t4 = t3 + (size_t)16384 * 256;
  unsigned short* t5 = t4 + (size_t)4096 * 256;
  unsigned short* partH = (unsigned short*)scratch;  // 8 x 2048 x 1024 f16 = 32MB
  unsigned short* h1 = (unsigned short*)(scratch + (size_t)8 * MPAD * 1024 * 2);
  unsigned short* h2 = h1 + (size_t)MPAD * 1024;

  // fused prep: proposals | tfeat(all) | w3 | twt(w2)
  k_prep<<<NB_PROP + NB_TF + NB_W3 + NB_TWT, 256, 0, stream>>>(
      (const float4*)anchors, (const float4*)rpn, (float4*)d_out,
      p2, p3, p4, p5, t2, t3, t4, t5, wc, wb, w3t, w2, w2t);
  k_tw1<<<dim3(8, 49), 256, 0, stream>>>(w1, w1t);
  k_roialign<<<MPAD, 256, 0, stream>>>(rois, t2, t3, t4, t5, xb);

  // GEMM1: 8 m-tiles x 4 n-tiles x ksplit 8 -> 256 blocks
  k_gemm1<<<256, 512, 0, stream>>>(xb, w1t, partH);
  k_reduce_relu<<<MPAD * 1024 / 8 / 256, 256, 0, stream>>>(partH, b1, h1);

  // GEMM2: [2048,1024]@[1024,1024] direct, 32x8=256 blocks, fused bias+relu
  k_gemm_dir<0, 128><<<256, 256, 0, stream>>>(h1, w2t, b2, nullptr, h2, nullptr, nullptr,
                                              1024, 8);

  // GEMM3: [2048,1024]@[1024,512] direct, BN=64 -> 32x8=256 blocks, fused scatter
  k_gemm_dir<1, 64><<<256, 256, 0, stream>>>(h2, w3t, bc, bb, nullptr, out_cls, out_bbox,
                                             512, 8);
}